// Round 15
// baseline (12368.954 us; speedup 1.0000x reference)
//
#include <hip/hip_runtime.h>
#include <math.h>

#define B_  32
#define T_  512
#define H_  512
#define A_  128
#define VD_ 512
#define V_  32000
#define NCHUNK 500   // 64-v logits chunks

__device__ __forceinline__ float sigf(float x){ return 1.f/(1.f+expf(-x)); }
__device__ __forceinline__ float dot4(float4 a, float4 b){ return a.x*b.x+a.y*b.y+a.z*b.z+a.w*b.w; }

struct DecArgs {
  const float *key, *value, *W_emb, *b_proj, *Wq, *bq, *W_ih, *W_hh, *b_ih, *b_hh, *Wm, *bm, *h00, *c00;
  const int* src_lens;
  float* out;
  float *hA, *hB, *c, *ctx, *projT, *logits, *lse, *pm, *ps;
  int *pidx, *idx;
  int* bar;    // [0] = logits done counter
  int L;
};

// ---------------- init h, c, idx
__global__ void k_init(DecArgs P) {
  int g = blockIdx.x*256 + threadIdx.x;
  if (g < B_*H_) { P.hA[g] = P.h00[g & (H_-1)]; P.c[g] = P.c00[g & (H_-1)]; }
  if (g < B_) P.idx[g] = 0;
}

// ---------------- gates GEMM + LSTM cell (blocks 0..255) || out[s-1] (256..511)
__global__ __launch_bounds__(256) void k_gatesout(DecArgs P, const float* hin,
                                                  float* hout, int s) {
  __shared__ float sm[3200];
  int bid = blockIdx.x, tid = threadIdx.x;
  if (bid < 256) {
    float* Wl   = sm;          // [64][9]  = 576
    float* xl   = sm + 576;    // [64][36] = 2304
    float* part = sm + 2880;   // [8][36]  = 288
    int*   idx_sh = (int*)(sm + 3168);
    const int kp = tid >> 5, jr = (tid >> 2) & 7, bg = tid & 3;
    if (tid < 32) idx_sh[tid] = P.idx[tid];
    float acc[8];
#pragma unroll
    for (int i = 0; i < 8; i++) acc[i] = 0.f;
    __syncthreads();

    // ---- register prefetch of window w staging data
    const int r = tid >> 4, iW = tid & 15;     // W stage coords (tid<128)
    const int gW = r >> 1, tlW = r & 1;
    const int jW = gW*512 + bid*2 + tlW;
    float4 wreg; float4 xreg[2];
    {  // load window 0
      if (tid < 128) wreg = *((const float4*)(P.W_ih + (size_t)jW*1024) + iW);
      int q = tid*2;
#pragma unroll
      for (int u = 0; u < 2; u++) {
        int b = (q+u) >> 4, i = (q+u) & 15;
        xreg[u] = *((const float4*)(P.W_emb + (size_t)idx_sh[b]*512) + i);
      }
    }

    for (int w = 0; w < 24; w++) {
      __syncthreads();
      if (tid < 128) {
        int kb = iW*4;
        Wl[(kb+0)*9+r]=wreg.x; Wl[(kb+1)*9+r]=wreg.y; Wl[(kb+2)*9+r]=wreg.z; Wl[(kb+3)*9+r]=wreg.w;
      }
      {
        int q = tid*2;
#pragma unroll
        for (int u = 0; u < 2; u++) {
          int b = (q+u) >> 4, i = (q+u) & 15;
          int kb = i*4;
          xl[(kb+0)*36+b]=xreg[u].x; xl[(kb+1)*36+b]=xreg[u].y;
          xl[(kb+2)*36+b]=xreg[u].z; xl[(kb+3)*36+b]=xreg[u].w;
        }
      }
      __syncthreads();
      if (w < 23) {   // prefetch window w+1
        int w1 = w + 1;
        if (tid < 128) {
          const float4* src = (w1 < 16)
            ? (const float4*)(P.W_ih + (size_t)jW*1024) + w1*16 + iW
            : (const float4*)(P.W_hh + (size_t)jW*512) + (w1-16)*16 + iW;
          wreg = *src;
        }
        int q = tid*2;
#pragma unroll
        for (int u = 0; u < 2; u++) {
          int b = (q+u) >> 4, i = (q+u) & 15;
          const float4* src;
          if (w1 < 8)       src = (const float4*)(P.W_emb + (size_t)idx_sh[b]*512) + w1*16 + i;
          else if (w1 < 16) src = (const float4*)(P.ctx + b*512) + (w1-8)*16 + i;
          else              src = (const float4*)(hin  + b*512) + (w1-16)*16 + i;
          xreg[u] = *src;
        }
      }
#pragma unroll
      for (int kk = 0; kk < 8; kk++) {
        int kl = kp*8 + kk;
        float wv = Wl[kl*9 + jr];
        const float4* xv = (const float4*)(xl + kl*36 + bg*8);
        float4 a0 = xv[0], a1 = xv[1];
        acc[0] += wv*a0.x; acc[1] += wv*a0.y; acc[2] += wv*a0.z; acc[3] += wv*a0.w;
        acc[4] += wv*a1.x; acc[5] += wv*a1.y; acc[6] += wv*a1.z; acc[7] += wv*a1.w;
      }
    }
    __syncthreads();
    for (int rd = 0; rd < 8; rd++) {
      if (kp == rd) {
        float* pr = part + jr*36 + bg*8;
        if (rd == 0) {
#pragma unroll
          for (int u = 0; u < 8; u++) pr[u] = acc[u];
        } else {
#pragma unroll
          for (int u = 0; u < 8; u++) pr[u] += acc[u];
        }
      }
      __syncthreads();
    }
    if (tid < 64) {
      int tl = tid >> 5, b = tid & 31;
      int t = bid*2 + tl;
      float gi = part[(0+tl)*36 + b] + P.b_ih[0*512+t] + P.b_hh[0*512+t];
      float gf = part[(2+tl)*36 + b] + P.b_ih[1*512+t] + P.b_hh[1*512+t];
      float gg = part[(4+tl)*36 + b] + P.b_ih[2*512+t] + P.b_hh[2*512+t];
      float go = part[(6+tl)*36 + b] + P.b_ih[3*512+t] + P.b_hh[3*512+t];
      float c0 = P.c[b*H_ + t];
      float c1 = sigf(gf)*c0 + sigf(gi)*tanhf(gg);
      P.c[b*H_ + t] = c1;
      hout[b*H_ + t] = sigf(go)*tanhf(c1);
    }
  } else if (s > 0) {
    int r2 = bid - 256;
    int bb = r2 >> 3, vs = r2 & 7;
    float l = P.lse[bb];
    const float4* lg = (const float4*)(P.logits + (size_t)bb*V_ + vs*4000);
    float4* o4 = (float4*)(P.out + ((size_t)bb*P.L + (s-1))*V_ + vs*4000);
    for (int i = tid; i < 1000; i += 256) {
      float4 x = lg[i];
      o4[i] = make_float4(x.x-l, x.y-l, x.z-l, x.w-l);
    }
  }
}

// ---------------- q + energy + masked softmax + ctx 32-col slice (512 blocks)
// block = vs*32 + b ; vs 0..15
__global__ __launch_bounds__(256) void k_att(DecArgs P, const float* hsrc) {
  __shared__ float sf[1408];
  int bid = blockIdx.x, tid = threadIdx.x;
  int b = bid & 31, vs = bid >> 5;
  float* h_sh   = sf;         // 512
  float* q_sh   = sf + 512;   // 128
  float* red    = sf + 640;   // 256
  float* att_sh = sf + 896;   // 512
  h_sh[tid]       = hsrc[b*H_ + tid];
  h_sh[tid + 256] = hsrc[b*H_ + tid + 256];
  __syncthreads();
  {  // q: all 256 threads, 2-way k split
    int a = tid & 127, half = tid >> 7;
    const float4* hv = (const float4*)h_sh + half*64;
    const float4* w  = (const float4*)(P.Wq + (size_t)a*H_) + half*64;
    float acc = 0.f;
#pragma unroll 8
    for (int k = 0; k < 64; k++) acc += dot4(w[k], hv[k]);
    red[tid] = acc;   // red doubles as qred
  }
  __syncthreads();
  if (tid < 128) q_sh[tid] = red[tid] + red[128 + tid] + P.bq[tid];
  __syncthreads();
  const float* kp = P.key + (size_t)b*A_*T_;
  float e0 = 0.f, e1 = 0.f;
#pragma unroll 8
  for (int a = 0; a < A_; a++) {
    float qa = q_sh[a];
    e0 += qa * kp[a*T_ + tid];
    e1 += qa * kp[a*T_ + tid + 256];
  }
  __syncthreads();   // red (qred) free now
  red[tid] = fmaxf(e0, e1);
  __syncthreads();
  for (int s2 = 128; s2 > 0; s2 >>= 1) { if (tid < s2) red[tid] = fmaxf(red[tid], red[tid+s2]); __syncthreads(); }
  float M = red[0];
  __syncthreads();
  int len = P.src_lens[b];
  float p0 = (tid       < len) ? expf(e0 - M) : 0.f;
  float p1 = (tid + 256 < len) ? expf(e1 - M) : 0.f;
  red[tid] = p0 + p1;
  __syncthreads();
  for (int s2 = 128; s2 > 0; s2 >>= 1) { if (tid < s2) red[tid] += red[tid+s2]; __syncthreads(); }
  float S = red[0];
  __syncthreads();
  att_sh[tid]       = p0 / S;
  att_sh[tid + 256] = p1 / S;
  __syncthreads();
  int vl = tid & 31, tq = tid >> 5;        // 8 t-groups of 64
  const float* vp = P.value + (size_t)b*T_*VD_ + vs*32 + vl;
  float acc = 0.f;
  int t0 = tq*64;
#pragma unroll 8
  for (int t = t0; t < t0 + 64; t++) acc += att_sh[t] * vp[(size_t)t*VD_];
  red[tid] = acc;
  __syncthreads();
  if (tid < 32) {
    float s2 = 0.f;
#pragma unroll
    for (int j = 0; j < 8; j++) s2 += red[j*32 + tid];
    P.ctx[b*VD_ + vs*32 + tid] = s2;
  }
}

// ---------------- proj GEMM (256 blocks, 2 m-rows each)
__global__ __launch_bounds__(256) void k_proj(DecArgs P) {
  __shared__ float sm[2600];
  int bid = blockIdx.x, tid = threadIdx.x;
  float* Wl   = sm;          // [64][3]
  float* xl   = sm + 192;    // [64][36]
  float* part = sm + 2496;   // [2][36]
  const int kp = tid >> 5, ml = (tid >> 4) & 1, bg = tid & 15;
  float acc0 = 0.f, acc1 = 0.f;

  for (int w = 0; w < 16; w++) {
    __syncthreads();
    if (tid < 32) {
      int r = tid >> 4, i = tid & 15;
      float4 x = *((const float4*)(P.Wm + (size_t)(bid*2+r)*1024) + w*16 + i);
      int kb = i*4;
      Wl[(kb+0)*3+r]=x.x; Wl[(kb+1)*3+r]=x.y; Wl[(kb+2)*3+r]=x.z; Wl[(kb+3)*3+r]=x.w;
    }
    {
      int q = tid*2;
#pragma unroll
      for (int u = 0; u < 2; u++, q++) {
        int b = q >> 4, i = q & 15;
        float4 x = (w < 8) ? *((const float4*)(P.c + b*512) + w*16 + i)
                           : *((const float4*)(P.ctx + b*512) + (w-8)*16 + i);
        int kb = i*4;
        xl[(kb+0)*36+b]=x.x; xl[(kb+1)*36+b]=x.y; xl[(kb+2)*36+b]=x.z; xl[(kb+3)*36+b]=x.w;
      }
    }
    __syncthreads();
#pragma unroll
    for (int kk = 0; kk < 8; kk++) {
      int kl = kp*8 + kk;
      float wv = Wl[kl*3 + ml];
      acc0 += wv * xl[kl*36 + bg*2];
      acc1 += wv * xl[kl*36 + bg*2 + 1];
    }
  }
  __syncthreads();
  for (int rd = 0; rd < 8; rd++) {
    if (kp == rd) {
      float* pr = part + ml*36 + bg*2;
      if (rd == 0) { pr[0] = acc0; pr[1] = acc1; }
      else         { pr[0] += acc0; pr[1] += acc1; }
    }
    __syncthreads();
  }
  if (tid < 64) {
    int ml2 = tid >> 5, b = tid & 31;
    int m = bid*2 + ml2;
    float s = part[ml2*36 + b] + P.bm[m];
    P.projT[m*32 + b] = (s > 0.f) ? s : 0.01f*s;
  }
}

// ---------------- merge all chunk partials -> lse/idx (run by last logits block)
__device__ __forceinline__ void merge_all(const DecArgs& P, int tid, float* sm) {
  int b = tid >> 3, g = tid & 7;
  float M = -INFINITY, S = 0.f; int I = 0x7fffffff;
  for (int ch = g; ch < NCHUNK; ch += 8) {       // ascending chunk order per lane
    float m2 = P.pm[ch*32+b], s2 = P.ps[ch*32+b]; int i2 = P.pidx[ch*32+b];
    if (m2 > M)       { S = S*expf(M-m2) + s2; M = m2; I = i2; }
    else if (m2 == M) { S += s2; I = min(I, i2); }
    else              { S += s2*expf(m2-M); }
  }
  float* mm = sm; float* ss = sm + 256; int* ii = (int*)(sm + 512);
  mm[tid] = M; ss[tid] = S; ii[tid] = I;
  __syncthreads();
  if (g == 0) {
    for (int j = 1; j < 8; j++) {
      float m2 = mm[b*8+j], s2 = ss[b*8+j]; int i2 = ii[b*8+j];
      if (m2 > M)       { S = S*expf(M-m2) + s2; M = m2; I = i2; }
      else if (m2 == M) { S += s2; I = min(I, i2); }
      else              { S += s2*expf(m2-M); }
    }
    P.lse[b] = M + logf(S);
    P.idx[b] = I;
  }
}

// ---------------- logits chunk (64 v) reg-tiled GEMM + partials + fused merge
__global__ __launch_bounds__(256) void k_logits(DecArgs P) {
  __shared__ float sm[9600];
  int bid = blockIdx.x, tid = threadIdx.x;
  const int v0 = bid * 64;
  float* Wl   = sm;            // [64k][68]
  float* pl   = sm + 4352;     // [64k][32]
  float* part = sm + 6400;     // [32b][68]
  const int kp = tid >> 5, vg = (tid >> 2) & 7, bg = tid & 3;
  const int sr = tid >> 2, skq = tid & 3;
  float acc[64];
#pragma unroll
  for (int i = 0; i < 64; i++) acc[i] = 0.f;

  const float* wrow = P.W_emb + (size_t)(v0 + sr)*H_ + skq*16;
  const float4* pbase = (const float4*)P.projT;
  float4 t0 = *((const float4*)(wrow + 0));
  float4 t1 = *((const float4*)(wrow + 4));
  float4 t2 = *((const float4*)(wrow + 8));
  float4 t3 = *((const float4*)(wrow + 12));
  float4 u0 = pbase[tid];
  float4 u1 = pbase[tid + 256];

  for (int w = 0; w < 8; w++) {
    __syncthreads();
    int kb = skq*16;
    Wl[(kb+ 0)*68+sr]=t0.x; Wl[(kb+ 1)*68+sr]=t0.y; Wl[(kb+ 2)*68+sr]=t0.z; Wl[(kb+ 3)*68+sr]=t0.w;
    Wl[(kb+ 4)*68+sr]=t1.x; Wl[(kb+ 5)*68+sr]=t1.y; Wl[(kb+ 6)*68+sr]=t1.z; Wl[(kb+ 7)*68+sr]=t1.w;
    Wl[(kb+ 8)*68+sr]=t2.x; Wl[(kb+ 9)*68+sr]=t2.y; Wl[(kb+10)*68+sr]=t2.z; Wl[(kb+11)*68+sr]=t2.w;
    Wl[(kb+12)*68+sr]=t3.x; Wl[(kb+13)*68+sr]=t3.y; Wl[(kb+14)*68+sr]=t3.z; Wl[(kb+15)*68+sr]=t3.w;
    ((float4*)pl)[tid]       = u0;
    ((float4*)pl)[tid + 256] = u1;
    __syncthreads();
    if (w < 7) {
      const float* wn = wrow + (w+1)*64;
      t0 = *((const float4*)(wn + 0));
      t1 = *((const float4*)(wn + 4));
      t2 = *((const float4*)(wn + 8));
      t3 = *((const float4*)(wn + 12));
      u0 = pbase[(w+1)*512 + tid];
      u1 = pbase[(w+1)*512 + tid + 256];
    }
#pragma unroll
    for (int kk = 0; kk < 8; kk++) {
      int kl = kp*8 + kk;
      float4 wv0 = *((const float4*)(Wl + kl*68 + vg*8));
      float4 wv1 = *((const float4*)(Wl + kl*68 + vg*8 + 4));
      float4 pv0 = *((const float4*)(pl + kl*32 + bg*8));
      float4 pv1 = *((const float4*)(pl + kl*32 + bg*8 + 4));
      float wa[8] = {wv0.x,wv0.y,wv0.z,wv0.w,wv1.x,wv1.y,wv1.z,wv1.w};
      float pa[8] = {pv0.x,pv0.y,pv0.z,pv0.w,pv1.x,pv1.y,pv1.z,pv1.w};
#pragma unroll
      for (int i = 0; i < 8; i++)
#pragma unroll
        for (int j = 0; j < 8; j++)
          acc[i*8+j] += wa[i]*pa[j];
    }
  }
  __syncthreads();
  if (kp == 0) {
#pragma unroll
    for (int j = 0; j < 8; j++) {
      int b = bg*8 + j;
      *((float4*)(part + b*68 + vg*8))     = make_float4(acc[0*8+j], acc[1*8+j], acc[2*8+j], acc[3*8+j]);
      *((float4*)(part + b*68 + vg*8 + 4)) = make_float4(acc[4*8+j], acc[5*8+j], acc[6*8+j], acc[7*8+j]);
    }
  }
  __syncthreads();
  for (int rd = 1; rd < 8; rd++) {
    if (kp == rd) {
#pragma unroll
      for (int j = 0; j < 8; j++) {
        int b = bg*8 + j;
        float4* q0 = (float4*)(part + b*68 + vg*8);
        float4* q1 = q0 + 1;
        float4 a0 = *q0, a1 = *q1;
        a0.x += acc[0*8+j]; a0.y += acc[1*8+j]; a0.z += acc[2*8+j]; a0.w += acc[3*8+j];
        a1.x += acc[4*8+j]; a1.y += acc[5*8+j]; a1.z += acc[6*8+j]; a1.w += acc[7*8+j];
        *q0 = a0; *q1 = a1;
      }
    }
    __syncthreads();
  }
  int b = tid >> 3, vq = tid & 7;
  float4 pA = *((const float4*)(part + b*68 + vq*8));
  float4 pB = *((const float4*)(part + b*68 + vq*8 + 4));
  int vb = v0 + vq*8;
  float x[8] = {pA.x,pA.y,pA.z,pA.w,pB.x,pB.y,pB.z,pB.w};
#pragma unroll
  for (int i = 0; i < 8; i++) x[i] += P.b_proj[vb + i];
  *((float4*)(P.logits + (size_t)b*V_ + vb))     = make_float4(x[0],x[1],x[2],x[3]);
  *((float4*)(P.logits + (size_t)b*V_ + vb + 4)) = make_float4(x[4],x[5],x[6],x[7]);
  float m = x[0], s = 1.f; int mi = vb;
#pragma unroll
  for (int i = 1; i < 8; i++) {
    if (x[i] > m) { s = s*expf(m - x[i]) + 1.f; m = x[i]; mi = vb + i; }
    else          { s += expf(x[i] - m); }
  }
  float* rm = sm; float* rs = sm + 256; int* ri = (int*)(sm + 512);
  __syncthreads();   // done with Wl region
  rm[vq*32 + b] = m; rs[vq*32 + b] = s; ri[vq*32 + b] = mi;
  __syncthreads();
  if (tid < 32) {
    int bb = tid;
    float M = rm[bb], S = rs[bb]; int I = ri[bb];
#pragma unroll
    for (int g = 1; g < 8; g++) {
      float m2 = rm[g*32+bb], s2 = rs[g*32+bb]; int i2 = ri[g*32+bb];
      if (m2 > M)       { S = S*expf(M - m2) + s2; M = m2; I = i2; }
      else if (m2 == M) { S += s2; I = min(I, i2); }
      else              { S += s2*expf(m2 - M); }
    }
    P.pm[bid*32 + bb] = M; P.ps[bid*32 + bb] = S; P.pidx[bid*32 + bb] = I;
  }
  // ---- fused merge: last chunk block to finish merges all partials
  __syncthreads();
  if (tid == 0) {
    int dc = __hip_atomic_fetch_add(P.bar, 1, __ATOMIC_ACQ_REL, __HIP_MEMORY_SCOPE_AGENT);
    ((int*)(sm + 1024))[0] = (dc == NCHUNK - 1) ? 1 : 0;
  }
  __syncthreads();
  int last = ((int*)(sm + 1024))[0];
  __syncthreads();
  if (last) {
    merge_all(P, tid, sm);
    __syncthreads();
    if (tid == 0) __hip_atomic_store(P.bar, 0, __ATOMIC_RELAXED, __HIP_MEMORY_SCOPE_AGENT);
  }
}

// ---------------- final out write (step L-1), 256 blocks
__global__ __launch_bounds__(256) void k_finalout(DecArgs P) {
  int bid = blockIdx.x, tid = threadIdx.x;
  int b = bid & 31, vs = bid >> 5;
  float l = P.lse[b];
  const float4* lg = (const float4*)(P.logits + (size_t)b*V_ + vs*4000);
  float4* o4 = (float4*)(P.out + ((size_t)b*P.L + (P.L-1))*V_ + vs*4000);
  for (int i = tid; i < 1000; i += 256) {
    float4 x = lg[i];
    o4[i] = make_float4(x.x-l, x.y-l, x.z-l, x.w-l);
  }
}

extern "C" void kernel_launch(void* const* d_in, const int* in_sizes, int n_in,
                              void* d_out, int out_size, void* d_ws, size_t ws_size,
                              hipStream_t stream) {
  DecArgs P;
  P.key      = (const float*)d_in[0];
  P.value    = (const float*)d_in[1];
  P.src_lens = (const int*)d_in[4];
  P.W_emb    = (const float*)d_in[5];
  P.b_proj   = (const float*)d_in[6];
  P.Wq       = (const float*)d_in[7];
  P.bq       = (const float*)d_in[8];
  P.W_ih     = (const float*)d_in[9];
  P.W_hh     = (const float*)d_in[10];
  P.b_ih     = (const float*)d_in[11];
  P.b_hh     = (const float*)d_in[12];
  P.Wm       = (const float*)d_in[13];
  P.bm       = (const float*)d_in[14];
  P.h00      = (const float*)d_in[15];
  P.c00      = (const float*)d_in[16];
  P.out      = (float*)d_out;
  P.L        = in_sizes[2] / B_;

  P.bar = (int*)d_ws;                 // 64 ints reserved
  float* ws = (float*)d_ws + 64;
  P.hA     = ws; ws += B_*H_;
  P.hB     = ws; ws += B_*H_;
  P.c      = ws; ws += B_*H_;
  P.ctx    = ws; ws += B_*VD_;
  P.projT  = ws; ws += H_*B_;
  P.lse    = ws; ws += 32;
  P.pm     = ws; ws += NCHUNK*B_;
  P.ps     = ws; ws += NCHUNK*B_;
  P.logits = ws; ws += (size_t)B_*V_;
  P.pidx   = (int*)ws; ws += NCHUNK*B_;
  P.idx    = (int*)ws;

  hipMemsetAsync(P.bar, 0, 64*sizeof(int), stream);
  k_init<<<64, 256, 0, stream>>>(P);
  k_att<<<512, 256, 0, stream>>>(P, P.hA);   // prologue attend with h0

  for (int s = 0; s < P.L; s++) {
    const float* hin  = (s & 1) ? P.hB : P.hA;
    float*       hout = (s & 1) ? P.hA : P.hB;
    k_gatesout<<<512, 256, 0, stream>>>(P, hin, hout, s);
    k_att<<<512, 256, 0, stream>>>(P, hout);
    k_proj<<<256, 256, 0, stream>>>(P);
    k_logits<<<NCHUNK, 256, 0, stream>>>(P);
  }
  k_finalout<<<256, 256, 0, stream>>>(P);
}

// Round 16
// 12193.507 us; speedup vs baseline: 1.0144x; 1.0144x over previous
//
#include <hip/hip_runtime.h>
#include <math.h>

#define B_  32
#define T_  512
#define H_  512
#define A_  128
#define VD_ 512
#define V_  32000
#define NCHUNK 500   // 64-v logits chunks

__device__ __forceinline__ float sigf(float x){ return 1.f/(1.f+expf(-x)); }
__device__ __forceinline__ float dot4(float4 a, float4 b){ return a.x*b.x+a.y*b.y+a.z*b.z+a.w*b.w; }

struct DecArgs {
  const float *key, *value, *W_emb, *b_proj, *Wq, *bq, *W_ih, *W_hh, *b_ih, *b_hh, *Wm, *bm, *h00, *c00;
  const int* src_lens;
  float* out;
  float *hA, *hB, *c, *ctx, *projT, *logits, *lse, *pm, *ps;
  int *pidx, *idx;
  int* bar;    // [0] = logits done counter
  int L;
};

// ---------------- init h, c, idx
__global__ void k_init(DecArgs P) {
  int g = blockIdx.x*256 + threadIdx.x;
  if (g < B_*H_) { P.hA[g] = P.h00[g & (H_-1)]; P.c[g] = P.c00[g & (H_-1)]; }
  if (g < B_) P.idx[g] = 0;
}

// ---------------- gates GEMM + LSTM cell (blocks 0..255) || out[s-1] (256..511)
// register-prefetched staging (R15 variant, refcheck-passed)
__global__ __launch_bounds__(256) void k_gatesout(DecArgs P, const float* hin,
                                                  float* hout, int s) {
  __shared__ float sm[3200];
  int bid = blockIdx.x, tid = threadIdx.x;
  if (bid < 256) {
    float* Wl   = sm;          // [64][9]  = 576
    float* xl   = sm + 576;    // [64][36] = 2304
    float* part = sm + 2880;   // [8][36]  = 288
    int*   idx_sh = (int*)(sm + 3168);
    const int kp = tid >> 5, jr = (tid >> 2) & 7, bg = tid & 3;
    if (tid < 32) idx_sh[tid] = P.idx[tid];
    float acc[8];
#pragma unroll
    for (int i = 0; i < 8; i++) acc[i] = 0.f;
    __syncthreads();

    const int r = tid >> 4, iW = tid & 15;     // W stage coords (tid<128)
    const int gW = r >> 1, tlW = r & 1;
    const int jW = gW*512 + bid*2 + tlW;
    float4 wreg; float4 xreg[2];
    {  // load window 0
      if (tid < 128) wreg = *((const float4*)(P.W_ih + (size_t)jW*1024) + iW);
      int q = tid*2;
#pragma unroll
      for (int u = 0; u < 2; u++) {
        int b = (q+u) >> 4, i = (q+u) & 15;
        xreg[u] = *((const float4*)(P.W_emb + (size_t)idx_sh[b]*512) + i);
      }
    }

    for (int w = 0; w < 24; w++) {
      __syncthreads();
      if (tid < 128) {
        int kb = iW*4;
        Wl[(kb+0)*9+r]=wreg.x; Wl[(kb+1)*9+r]=wreg.y; Wl[(kb+2)*9+r]=wreg.z; Wl[(kb+3)*9+r]=wreg.w;
      }
      {
        int q = tid*2;
#pragma unroll
        for (int u = 0; u < 2; u++) {
          int b = (q+u) >> 4, i = (q+u) & 15;
          int kb = i*4;
          xl[(kb+0)*36+b]=xreg[u].x; xl[(kb+1)*36+b]=xreg[u].y;
          xl[(kb+2)*36+b]=xreg[u].z; xl[(kb+3)*36+b]=xreg[u].w;
        }
      }
      __syncthreads();
      if (w < 23) {   // prefetch window w+1 (overlaps with FMA below)
        int w1 = w + 1;
        if (tid < 128) {
          const float4* src = (w1 < 16)
            ? (const float4*)(P.W_ih + (size_t)jW*1024) + w1*16 + iW
            : (const float4*)(P.W_hh + (size_t)jW*512) + (w1-16)*16 + iW;
          wreg = *src;
        }
        int q = tid*2;
#pragma unroll
        for (int u = 0; u < 2; u++) {
          int b = (q+u) >> 4, i = (q+u) & 15;
          const float4* src;
          if (w1 < 8)       src = (const float4*)(P.W_emb + (size_t)idx_sh[b]*512) + w1*16 + i;
          else if (w1 < 16) src = (const float4*)(P.ctx + b*512) + (w1-8)*16 + i;
          else              src = (const float4*)(hin  + b*512) + (w1-16)*16 + i;
          xreg[u] = *src;
        }
      }
#pragma unroll
      for (int kk = 0; kk < 8; kk++) {
        int kl = kp*8 + kk;
        float wv = Wl[kl*9 + jr];
        const float4* xv = (const float4*)(xl + kl*36 + bg*8);
        float4 a0 = xv[0], a1 = xv[1];
        acc[0] += wv*a0.x; acc[1] += wv*a0.y; acc[2] += wv*a0.z; acc[3] += wv*a0.w;
        acc[4] += wv*a1.x; acc[5] += wv*a1.y; acc[6] += wv*a1.z; acc[7] += wv*a1.w;
      }
    }
    __syncthreads();
    for (int rd = 0; rd < 8; rd++) {
      if (kp == rd) {
        float* pr = part + jr*36 + bg*8;
        if (rd == 0) {
#pragma unroll
          for (int u = 0; u < 8; u++) pr[u] = acc[u];
        } else {
#pragma unroll
          for (int u = 0; u < 8; u++) pr[u] += acc[u];
        }
      }
      __syncthreads();
    }
    if (tid < 64) {
      int tl = tid >> 5, b = tid & 31;
      int t = bid*2 + tl;
      float gi = part[(0+tl)*36 + b] + P.b_ih[0*512+t] + P.b_hh[0*512+t];
      float gf = part[(2+tl)*36 + b] + P.b_ih[1*512+t] + P.b_hh[1*512+t];
      float gg = part[(4+tl)*36 + b] + P.b_ih[2*512+t] + P.b_hh[2*512+t];
      float go = part[(6+tl)*36 + b] + P.b_ih[3*512+t] + P.b_hh[3*512+t];
      float c0 = P.c[b*H_ + t];
      float c1 = sigf(gf)*c0 + sigf(gi)*tanhf(gg);
      P.c[b*H_ + t] = c1;
      hout[b*H_ + t] = sigf(go)*tanhf(c1);
    }
  } else if (s > 0) {
    int r2 = bid - 256;
    int bb = r2 >> 3, vs = r2 & 7;
    float l = P.lse[bb];
    const float4* lg = (const float4*)(P.logits + (size_t)bb*V_ + vs*4000);
    float4* o4 = (float4*)(P.out + ((size_t)bb*P.L + (s-1))*V_ + vs*4000);
    for (int i = tid; i < 1000; i += 256) {
      float4 x = lg[i];
      o4[i] = make_float4(x.x-l, x.y-l, x.z-l, x.w-l);
    }
  }
}

// ---------------- q + energy + masked softmax + ctx 64-col slice (256 blocks, R14)
__global__ __launch_bounds__(256) void k_att(DecArgs P, const float* hsrc) {
  __shared__ float sf[1408];
  int bid = blockIdx.x, tid = threadIdx.x;
  int b = bid & 31, vs = bid >> 5;
  float* h_sh   = sf;         // 512
  float* q_sh   = sf + 512;   // 128
  float* red    = sf + 640;   // 256
  float* att_sh = sf + 896;   // 512
  h_sh[tid]       = hsrc[b*H_ + tid];
  h_sh[tid + 256] = hsrc[b*H_ + tid + 256];
  __syncthreads();
  if (tid < 128) {
    const float4* hv = (const float4*)h_sh;
    const float4* w  = (const float4*)(P.Wq + (size_t)tid*H_);
    float acc = P.bq[tid];
#pragma unroll 8
    for (int k = 0; k < 128; k++) acc += dot4(w[k], hv[k]);
    q_sh[tid] = acc;
  }
  __syncthreads();
  const float* kp = P.key + (size_t)b*A_*T_;
  float e0 = 0.f, e1 = 0.f;
#pragma unroll 8
  for (int a = 0; a < A_; a++) {
    float qa = q_sh[a];
    e0 += qa * kp[a*T_ + tid];
    e1 += qa * kp[a*T_ + tid + 256];
  }
  red[tid] = fmaxf(e0, e1);
  __syncthreads();
  for (int s2 = 128; s2 > 0; s2 >>= 1) { if (tid < s2) red[tid] = fmaxf(red[tid], red[tid+s2]); __syncthreads(); }
  float M = red[0];
  __syncthreads();
  int len = P.src_lens[b];
  float p0 = (tid       < len) ? expf(e0 - M) : 0.f;
  float p1 = (tid + 256 < len) ? expf(e1 - M) : 0.f;
  red[tid] = p0 + p1;
  __syncthreads();
  for (int s2 = 128; s2 > 0; s2 >>= 1) { if (tid < s2) red[tid] += red[tid+s2]; __syncthreads(); }
  float S = red[0];
  __syncthreads();
  att_sh[tid]       = p0 / S;
  att_sh[tid + 256] = p1 / S;
  __syncthreads();
  int vl = tid & 63, tq = tid >> 6;
  int v = vs*64 + vl;
  const float* vp = P.value + (size_t)b*T_*VD_ + v;
  float acc = 0.f;
  int t0 = tq*128;
#pragma unroll 8
  for (int t = t0; t < t0 + 128; t++) acc += att_sh[t] * vp[(size_t)t*VD_];
  red[tid] = acc;
  __syncthreads();
  if (tid < 64) P.ctx[b*VD_ + vs*64 + tid] = red[tid] + red[tid+64] + red[tid+128] + red[tid+192];
}

// ---------------- proj GEMM (256 blocks, 2 m-rows each)
__global__ __launch_bounds__(256) void k_proj(DecArgs P) {
  __shared__ float sm[2600];
  int bid = blockIdx.x, tid = threadIdx.x;
  float* Wl   = sm;          // [64][3]
  float* xl   = sm + 192;    // [64][36]
  float* part = sm + 2496;   // [2][36]
  const int kp = tid >> 5, ml = (tid >> 4) & 1, bg = tid & 15;
  float acc0 = 0.f, acc1 = 0.f;

  for (int w = 0; w < 16; w++) {
    __syncthreads();
    if (tid < 32) {
      int r = tid >> 4, i = tid & 15;
      float4 x = *((const float4*)(P.Wm + (size_t)(bid*2+r)*1024) + w*16 + i);
      int kb = i*4;
      Wl[(kb+0)*3+r]=x.x; Wl[(kb+1)*3+r]=x.y; Wl[(kb+2)*3+r]=x.z; Wl[(kb+3)*3+r]=x.w;
    }
    {
      int q = tid*2;
#pragma unroll
      for (int u = 0; u < 2; u++, q++) {
        int b = q >> 4, i = q & 15;
        float4 x = (w < 8) ? *((const float4*)(P.c + b*512) + w*16 + i)
                           : *((const float4*)(P.ctx + b*512) + (w-8)*16 + i);
        int kb = i*4;
        xl[(kb+0)*36+b]=x.x; xl[(kb+1)*36+b]=x.y; xl[(kb+2)*36+b]=x.z; xl[(kb+3)*36+b]=x.w;
      }
    }
    __syncthreads();
#pragma unroll
    for (int kk = 0; kk < 8; kk++) {
      int kl = kp*8 + kk;
      float wv = Wl[kl*3 + ml];
      acc0 += wv * xl[kl*36 + bg*2];
      acc1 += wv * xl[kl*36 + bg*2 + 1];
    }
  }
  __syncthreads();
  for (int rd = 0; rd < 8; rd++) {
    if (kp == rd) {
      float* pr = part + ml*36 + bg*2;
      if (rd == 0) { pr[0] = acc0; pr[1] = acc1; }
      else         { pr[0] += acc0; pr[1] += acc1; }
    }
    __syncthreads();
  }
  if (tid < 64) {
    int ml2 = tid >> 5, b = tid & 31;
    int m = bid*2 + ml2;
    float s = part[ml2*36 + b] + P.bm[m];
    P.projT[m*32 + b] = (s > 0.f) ? s : 0.01f*s;
  }
}

// ---------------- merge all chunk partials -> lse/idx (run by last logits block)
__device__ __forceinline__ void merge_all(const DecArgs& P, int tid, float* sm) {
  int b = tid >> 3, g = tid & 7;
  float M = -INFINITY, S = 0.f; int I = 0x7fffffff;
  for (int ch = g; ch < NCHUNK; ch += 8) {       // ascending chunk order per lane
    float m2 = P.pm[ch*32+b], s2 = P.ps[ch*32+b]; int i2 = P.pidx[ch*32+b];
    if (m2 > M)       { S = S*expf(M-m2) + s2; M = m2; I = i2; }
    else if (m2 == M) { S += s2; I = min(I, i2); }
    else              { S += s2*expf(m2-M); }
  }
  float* mm = sm; float* ss = sm + 256; int* ii = (int*)(sm + 512);
  mm[tid] = M; ss[tid] = S; ii[tid] = I;
  __syncthreads();
  if (g == 0) {
    for (int j = 1; j < 8; j++) {
      float m2 = mm[b*8+j], s2 = ss[b*8+j]; int i2 = ii[b*8+j];
      if (m2 > M)       { S = S*expf(M-m2) + s2; M = m2; I = i2; }
      else if (m2 == M) { S += s2; I = min(I, i2); }
      else              { S += s2*expf(m2-M); }
    }
    P.lse[b] = M + logf(S);
    P.idx[b] = I;
  }
}

// ---------------- logits chunk (64 v) reg-tiled GEMM + partials + fused merge
__global__ __launch_bounds__(256) void k_logits(DecArgs P) {
  __shared__ float sm[9600];
  int bid = blockIdx.x, tid = threadIdx.x;
  const int v0 = bid * 64;
  float* Wl   = sm;            // [64k][68]
  float* pl   = sm + 4352;     // [64k][32]
  float* part = sm + 6400;     // [32b][68]
  const int kp = tid >> 5, vg = (tid >> 2) & 7, bg = tid & 3;
  const int sr = tid >> 2, skq = tid & 3;
  float acc[64];
#pragma unroll
  for (int i = 0; i < 64; i++) acc[i] = 0.f;

  const float* wrow = P.W_emb + (size_t)(v0 + sr)*H_ + skq*16;
  const float4* pbase = (const float4*)P.projT;
  float4 t0 = *((const float4*)(wrow + 0));
  float4 t1 = *((const float4*)(wrow + 4));
  float4 t2 = *((const float4*)(wrow + 8));
  float4 t3 = *((const float4*)(wrow + 12));
  float4 u0 = pbase[tid];
  float4 u1 = pbase[tid + 256];

  for (int w = 0; w < 8; w++) {
    __syncthreads();
    int kb = skq*16;
    Wl[(kb+ 0)*68+sr]=t0.x; Wl[(kb+ 1)*68+sr]=t0.y; Wl[(kb+ 2)*68+sr]=t0.z; Wl[(kb+ 3)*68+sr]=t0.w;
    Wl[(kb+ 4)*68+sr]=t1.x; Wl[(kb+ 5)*68+sr]=t1.y; Wl[(kb+ 6)*68+sr]=t1.z; Wl[(kb+ 7)*68+sr]=t1.w;
    Wl[(kb+ 8)*68+sr]=t2.x; Wl[(kb+ 9)*68+sr]=t2.y; Wl[(kb+10)*68+sr]=t2.z; Wl[(kb+11)*68+sr]=t2.w;
    Wl[(kb+12)*68+sr]=t3.x; Wl[(kb+13)*68+sr]=t3.y; Wl[(kb+14)*68+sr]=t3.z; Wl[(kb+15)*68+sr]=t3.w;
    ((float4*)pl)[tid]       = u0;
    ((float4*)pl)[tid + 256] = u1;
    __syncthreads();
    if (w < 7) {
      const float* wn = wrow + (w+1)*64;
      t0 = *((const float4*)(wn + 0));
      t1 = *((const float4*)(wn + 4));
      t2 = *((const float4*)(wn + 8));
      t3 = *((const float4*)(wn + 12));
      u0 = pbase[(w+1)*512 + tid];
      u1 = pbase[(w+1)*512 + tid + 256];
    }
#pragma unroll
    for (int kk = 0; kk < 8; kk++) {
      int kl = kp*8 + kk;
      float4 wv0 = *((const float4*)(Wl + kl*68 + vg*8));
      float4 wv1 = *((const float4*)(Wl + kl*68 + vg*8 + 4));
      float4 pv0 = *((const float4*)(pl + kl*32 + bg*8));
      float4 pv1 = *((const float4*)(pl + kl*32 + bg*8 + 4));
      float wa[8] = {wv0.x,wv0.y,wv0.z,wv0.w,wv1.x,wv1.y,wv1.z,wv1.w};
      float pa[8] = {pv0.x,pv0.y,pv0.z,pv0.w,pv1.x,pv1.y,pv1.z,pv1.w};
#pragma unroll
      for (int i = 0; i < 8; i++)
#pragma unroll
        for (int j = 0; j < 8; j++)
          acc[i*8+j] += wa[i]*pa[j];
    }
  }
  __syncthreads();
  if (kp == 0) {
#pragma unroll
    for (int j = 0; j < 8; j++) {
      int b = bg*8 + j;
      *((float4*)(part + b*68 + vg*8))     = make_float4(acc[0*8+j], acc[1*8+j], acc[2*8+j], acc[3*8+j]);
      *((float4*)(part + b*68 + vg*8 + 4)) = make_float4(acc[4*8+j], acc[5*8+j], acc[6*8+j], acc[7*8+j]);
    }
  }
  __syncthreads();
  for (int rd = 1; rd < 8; rd++) {
    if (kp == rd) {
#pragma unroll
      for (int j = 0; j < 8; j++) {
        int b = bg*8 + j;
        float4* q0 = (float4*)(part + b*68 + vg*8);
        float4* q1 = q0 + 1;
        float4 a0 = *q0, a1 = *q1;
        a0.x += acc[0*8+j]; a0.y += acc[1*8+j]; a0.z += acc[2*8+j]; a0.w += acc[3*8+j];
        a1.x += acc[4*8+j]; a1.y += acc[5*8+j]; a1.z += acc[6*8+j]; a1.w += acc[7*8+j];
        *q0 = a0; *q1 = a1;
      }
    }
    __syncthreads();
  }
  int b = tid >> 3, vq = tid & 7;
  float4 pA = *((const float4*)(part + b*68 + vq*8));
  float4 pB = *((const float4*)(part + b*68 + vq*8 + 4));
  int vb = v0 + vq*8;
  float x[8] = {pA.x,pA.y,pA.z,pA.w,pB.x,pB.y,pB.z,pB.w};
#pragma unroll
  for (int i = 0; i < 8; i++) x[i] += P.b_proj[vb + i];
  *((float4*)(P.logits + (size_t)b*V_ + vb))     = make_float4(x[0],x[1],x[2],x[3]);
  *((float4*)(P.logits + (size_t)b*V_ + vb + 4)) = make_float4(x[4],x[5],x[6],x[7]);
  float m = x[0], s = 1.f; int mi = vb;
#pragma unroll
  for (int i = 1; i < 8; i++) {
    if (x[i] > m) { s = s*expf(m - x[i]) + 1.f; m = x[i]; mi = vb + i; }
    else          { s += expf(x[i] - m); }
  }
  float* rm = sm; float* rs = sm + 256; int* ri = (int*)(sm + 512);
  __syncthreads();   // done with Wl region
  rm[vq*32 + b] = m; rs[vq*32 + b] = s; ri[vq*32 + b] = mi;
  __syncthreads();
  if (tid < 32) {
    int bb = tid;
    float M = rm[bb], S = rs[bb]; int I = ri[bb];
#pragma unroll
    for (int g = 1; g < 8; g++) {
      float m2 = rm[g*32+bb], s2 = rs[g*32+bb]; int i2 = ri[g*32+bb];
      if (m2 > M)       { S = S*expf(M - m2) + s2; M = m2; I = i2; }
      else if (m2 == M) { S += s2; I = min(I, i2); }
      else              { S += s2*expf(m2 - M); }
    }
    P.pm[bid*32 + bb] = M; P.ps[bid*32 + bb] = S; P.pidx[bid*32 + bb] = I;
  }
  // ---- fused merge: last chunk block to finish merges all partials
  __syncthreads();
  if (tid == 0) {
    int dc = __hip_atomic_fetch_add(P.bar, 1, __ATOMIC_ACQ_REL, __HIP_MEMORY_SCOPE_AGENT);
    ((int*)(sm + 1024))[0] = (dc == NCHUNK - 1) ? 1 : 0;
  }
  __syncthreads();
  int last = ((int*)(sm + 1024))[0];
  __syncthreads();
  if (last) {
    merge_all(P, tid, sm);
    __syncthreads();
    if (tid == 0) __hip_atomic_store(P.bar, 0, __ATOMIC_RELAXED, __HIP_MEMORY_SCOPE_AGENT);
  }
}

// ---------------- final out write (step L-1), 256 blocks
__global__ __launch_bounds__(256) void k_finalout(DecArgs P) {
  int bid = blockIdx.x, tid = threadIdx.x;
  int b = bid & 31, vs = bid >> 5;
  float l = P.lse[b];
  const float4* lg = (const float4*)(P.logits + (size_t)b*V_ + vs*4000);
  float4* o4 = (float4*)(P.out + ((size_t)b*P.L + (P.L-1))*V_ + vs*4000);
  for (int i = tid; i < 1000; i += 256) {
    float4 x = lg[i];
    o4[i] = make_float4(x.x-l, x.y-l, x.z-l, x.w-l);
  }
}

extern "C" void kernel_launch(void* const* d_in, const int* in_sizes, int n_in,
                              void* d_out, int out_size, void* d_ws, size_t ws_size,
                              hipStream_t stream) {
  DecArgs P;
  P.key      = (const float*)d_in[0];
  P.value    = (const float*)d_in[1];
  P.src_lens = (const int*)d_in[4];
  P.W_emb    = (const float*)d_in[5];
  P.b_proj   = (const float*)d_in[6];
  P.Wq       = (const float*)d_in[7];
  P.bq       = (const float*)d_in[8];
  P.W_ih     = (const float*)d_in[9];
  P.W_hh     = (const float*)d_in[10];
  P.b_ih     = (const float*)d_in[11];
  P.b_hh     = (const float*)d_in[12];
  P.Wm       = (const float*)d_in[13];
  P.bm       = (const float*)d_in[14];
  P.h00      = (const float*)d_in[15];
  P.c00      = (const float*)d_in[16];
  P.out      = (float*)d_out;
  P.L        = in_sizes[2] / B_;

  P.bar = (int*)d_ws;                 // 64 ints reserved
  float* ws = (float*)d_ws + 64;
  P.hA     = ws; ws += B_*H_;
  P.hB     = ws; ws += B_*H_;
  P.c      = ws; ws += B_*H_;
  P.ctx    = ws; ws += B_*VD_;
  P.projT  = ws; ws += H_*B_;
  P.lse    = ws; ws += 32;
  P.pm     = ws; ws += NCHUNK*B_;
  P.ps     = ws; ws += NCHUNK*B_;
  P.logits = ws; ws += (size_t)B_*V_;
  P.pidx   = (int*)ws; ws += NCHUNK*B_;
  P.idx    = (int*)ws;

  hipMemsetAsync(P.bar, 0, 64*sizeof(int), stream);
  k_init<<<64, 256, 0, stream>>>(P);
  k_att<<<256, 256, 0, stream>>>(P, P.hA);   // prologue attend with h0

  for (int s = 0; s < P.L; s++) {
    const float* hin  = (s & 1) ? P.hB : P.hA;
    float*       hout = (s & 1) ? P.hA : P.hB;
    k_gatesout<<<512, 256, 0, stream>>>(P, hin, hout, s);
    k_att<<<256, 256, 0, stream>>>(P, hout);
    k_proj<<<256, 256, 0, stream>>>(P);
    k_logits<<<NCHUNK, 256, 0, stream>>>(P);
  }
  k_finalout<<<256, 256, 0, stream>>>(P);
}

// Round 17
// 9211.834 us; speedup vs baseline: 1.3427x; 1.3237x over previous
//
#include <hip/hip_runtime.h>
#include <math.h>

#define B_  32
#define T_  512
#define H_  512
#define A_  128
#define VD_ 512
#define V_  32000
#define NCHUNK 500   // 64-v logits chunks

__device__ __forceinline__ float sigf(float x){ return 1.f/(1.f+expf(-x)); }
__device__ __forceinline__ float dot4(float4 a, float4 b){ return a.x*b.x+a.y*b.y+a.z*b.z+a.w*b.w; }

struct DecArgs {
  const float *key, *value, *W_emb, *b_proj, *Wq, *bq, *W_ih, *W_hh, *b_ih, *b_hh, *Wm, *bm, *h00, *c00;
  const int* src_lens;
  float* out;
  float *hA, *hB, *c, *ctx, *projT, *logits, *lse, *pm, *ps;
  int *pidx, *idx;
  int L;
};

// ---------------- init h, c, idx
__global__ void k_init(DecArgs P) {
  int g = blockIdx.x*256 + threadIdx.x;
  if (g < B_*H_) { P.hA[g] = P.h00[g & (H_-1)]; P.c[g] = P.c00[g & (H_-1)]; }
  if (g < B_) P.idx[g] = 0;
}

// ---------------- gates GEMM + LSTM cell (blocks 0..255) || out[s-1] (256..511)
// ONLY change vs R14: register-prefetched staging of W / x windows
__global__ __launch_bounds__(256) void k_gatesout(DecArgs P, const float* hin,
                                                  float* hout, int s) {
  __shared__ float sm[3200];
  int bid = blockIdx.x, tid = threadIdx.x;
  if (bid < 256) {
    float* Wl   = sm;          // [64][9]  = 576
    float* xl   = sm + 576;    // [64][36] = 2304
    float* part = sm + 2880;   // [8][36]  = 288
    int*   idx_sh = (int*)(sm + 3168);
    const int kp = tid >> 5, jr = (tid >> 2) & 7, bg = tid & 3;
    if (tid < 32) idx_sh[tid] = P.idx[tid];
    float acc[8];
#pragma unroll
    for (int i = 0; i < 8; i++) acc[i] = 0.f;
    __syncthreads();

    const int r = tid >> 4, iW = tid & 15;     // W stage coords (tid<128)
    const int gW = r >> 1, tlW = r & 1;
    const int jW = gW*512 + bid*2 + tlW;
    float4 wreg; float4 xreg[2];
    {  // load window 0
      if (tid < 128) wreg = *((const float4*)(P.W_ih + (size_t)jW*1024) + iW);
      int q = tid*2;
#pragma unroll
      for (int u = 0; u < 2; u++) {
        int b = (q+u) >> 4, i = (q+u) & 15;
        xreg[u] = *((const float4*)(P.W_emb + (size_t)idx_sh[b]*512) + i);
      }
    }

    for (int w = 0; w < 24; w++) {
      __syncthreads();
      if (tid < 128) {
        int kb = iW*4;
        Wl[(kb+0)*9+r]=wreg.x; Wl[(kb+1)*9+r]=wreg.y; Wl[(kb+2)*9+r]=wreg.z; Wl[(kb+3)*9+r]=wreg.w;
      }
      {
        int q = tid*2;
#pragma unroll
        for (int u = 0; u < 2; u++) {
          int b = (q+u) >> 4, i = (q+u) & 15;
          int kb = i*4;
          xl[(kb+0)*36+b]=xreg[u].x; xl[(kb+1)*36+b]=xreg[u].y;
          xl[(kb+2)*36+b]=xreg[u].z; xl[(kb+3)*36+b]=xreg[u].w;
        }
      }
      __syncthreads();
      if (w < 23) {   // prefetch window w+1 (overlaps FMA below)
        int w1 = w + 1;
        if (tid < 128) {
          const float4* src = (w1 < 16)
            ? (const float4*)(P.W_ih + (size_t)jW*1024) + w1*16 + iW
            : (const float4*)(P.W_hh + (size_t)jW*512) + (w1-16)*16 + iW;
          wreg = *src;
        }
        int q = tid*2;
#pragma unroll
        for (int u = 0; u < 2; u++) {
          int b = (q+u) >> 4, i = (q+u) & 15;
          const float4* src;
          if (w1 < 8)       src = (const float4*)(P.W_emb + (size_t)idx_sh[b]*512) + w1*16 + i;
          else if (w1 < 16) src = (const float4*)(P.ctx + b*512) + (w1-8)*16 + i;
          else              src = (const float4*)(hin  + b*512) + (w1-16)*16 + i;
          xreg[u] = *src;
        }
      }
#pragma unroll
      for (int kk = 0; kk < 8; kk++) {
        int kl = kp*8 + kk;
        float wv = Wl[kl*9 + jr];
        const float4* xv = (const float4*)(xl + kl*36 + bg*8);
        float4 a0 = xv[0], a1 = xv[1];
        acc[0] += wv*a0.x; acc[1] += wv*a0.y; acc[2] += wv*a0.z; acc[3] += wv*a0.w;
        acc[4] += wv*a1.x; acc[5] += wv*a1.y; acc[6] += wv*a1.z; acc[7] += wv*a1.w;
      }
    }
    __syncthreads();
    for (int rd = 0; rd < 8; rd++) {
      if (kp == rd) {
        float* pr = part + jr*36 + bg*8;
        if (rd == 0) {
#pragma unroll
          for (int u = 0; u < 8; u++) pr[u] = acc[u];
        } else {
#pragma unroll
          for (int u = 0; u < 8; u++) pr[u] += acc[u];
        }
      }
      __syncthreads();
    }
    if (tid < 64) {
      int tl = tid >> 5, b = tid & 31;
      int t = bid*2 + tl;
      float gi = part[(0+tl)*36 + b] + P.b_ih[0*512+t] + P.b_hh[0*512+t];
      float gf = part[(2+tl)*36 + b] + P.b_ih[1*512+t] + P.b_hh[1*512+t];
      float gg = part[(4+tl)*36 + b] + P.b_ih[2*512+t] + P.b_hh[2*512+t];
      float go = part[(6+tl)*36 + b] + P.b_ih[3*512+t] + P.b_hh[3*512+t];
      float c0 = P.c[b*H_ + t];
      float c1 = sigf(gf)*c0 + sigf(gi)*tanhf(gg);
      P.c[b*H_ + t] = c1;
      hout[b*H_ + t] = sigf(go)*tanhf(c1);
    }
  } else if (s > 0) {
    int r2 = bid - 256;
    int bb = r2 >> 3, vs = r2 & 7;
    float l = P.lse[bb];
    const float4* lg = (const float4*)(P.logits + (size_t)bb*V_ + vs*4000);
    float4* o4 = (float4*)(P.out + ((size_t)bb*P.L + (s-1))*V_ + vs*4000);
    for (int i = tid; i < 1000; i += 256) {
      float4 x = lg[i];
      o4[i] = make_float4(x.x-l, x.y-l, x.z-l, x.w-l);
    }
  }
}

// ---------------- q + energy + masked softmax + ctx 64-col slice (256 blocks, R14)
__global__ __launch_bounds__(256) void k_att(DecArgs P, const float* hsrc) {
  __shared__ float sf[1408];
  int bid = blockIdx.x, tid = threadIdx.x;
  int b = bid & 31, vs = bid >> 5;
  float* h_sh   = sf;         // 512
  float* q_sh   = sf + 512;   // 128
  float* red    = sf + 640;   // 256
  float* att_sh = sf + 896;   // 512
  h_sh[tid]       = hsrc[b*H_ + tid];
  h_sh[tid + 256] = hsrc[b*H_ + tid + 256];
  __syncthreads();
  if (tid < 128) {
    const float4* hv = (const float4*)h_sh;
    const float4* w  = (const float4*)(P.Wq + (size_t)tid*H_);
    float acc = P.bq[tid];
#pragma unroll 8
    for (int k = 0; k < 128; k++) acc += dot4(w[k], hv[k]);
    q_sh[tid] = acc;
  }
  __syncthreads();
  const float* kp = P.key + (size_t)b*A_*T_;
  float e0 = 0.f, e1 = 0.f;
#pragma unroll 8
  for (int a = 0; a < A_; a++) {
    float qa = q_sh[a];
    e0 += qa * kp[a*T_ + tid];
    e1 += qa * kp[a*T_ + tid + 256];
  }
  red[tid] = fmaxf(e0, e1);
  __syncthreads();
  for (int s2 = 128; s2 > 0; s2 >>= 1) { if (tid < s2) red[tid] = fmaxf(red[tid], red[tid+s2]); __syncthreads(); }
  float M = red[0];
  __syncthreads();
  int len = P.src_lens[b];
  float p0 = (tid       < len) ? expf(e0 - M) : 0.f;
  float p1 = (tid + 256 < len) ? expf(e1 - M) : 0.f;
  red[tid] = p0 + p1;
  __syncthreads();
  for (int s2 = 128; s2 > 0; s2 >>= 1) { if (tid < s2) red[tid] += red[tid+s2]; __syncthreads(); }
  float S = red[0];
  __syncthreads();
  att_sh[tid]       = p0 / S;
  att_sh[tid + 256] = p1 / S;
  __syncthreads();
  int vl = tid & 63, tq = tid >> 6;
  int v = vs*64 + vl;
  const float* vp = P.value + (size_t)b*T_*VD_ + v;
  float acc = 0.f;
  int t0 = tq*128;
#pragma unroll 8
  for (int t = t0; t < t0 + 128; t++) acc += att_sh[t] * vp[(size_t)t*VD_];
  red[tid] = acc;
  __syncthreads();
  if (tid < 64) P.ctx[b*VD_ + vs*64 + tid] = red[tid] + red[tid+64] + red[tid+128] + red[tid+192];
}

// ---------------- proj GEMM (256 blocks, 2 m-rows each)
__global__ __launch_bounds__(256) void k_proj(DecArgs P) {
  __shared__ float sm[2600];
  int bid = blockIdx.x, tid = threadIdx.x;
  float* Wl   = sm;          // [64][3]
  float* xl   = sm + 192;    // [64][36]
  float* part = sm + 2496;   // [2][36]
  const int kp = tid >> 5, ml = (tid >> 4) & 1, bg = tid & 15;
  float acc0 = 0.f, acc1 = 0.f;

  for (int w = 0; w < 16; w++) {
    __syncthreads();
    if (tid < 32) {
      int r = tid >> 4, i = tid & 15;
      float4 x = *((const float4*)(P.Wm + (size_t)(bid*2+r)*1024) + w*16 + i);
      int kb = i*4;
      Wl[(kb+0)*3+r]=x.x; Wl[(kb+1)*3+r]=x.y; Wl[(kb+2)*3+r]=x.z; Wl[(kb+3)*3+r]=x.w;
    }
    {
      int q = tid*2;
#pragma unroll
      for (int u = 0; u < 2; u++, q++) {
        int b = q >> 4, i = q & 15;
        float4 x = (w < 8) ? *((const float4*)(P.c + b*512) + w*16 + i)
                           : *((const float4*)(P.ctx + b*512) + (w-8)*16 + i);
        int kb = i*4;
        xl[(kb+0)*36+b]=x.x; xl[(kb+1)*36+b]=x.y; xl[(kb+2)*36+b]=x.z; xl[(kb+3)*36+b]=x.w;
      }
    }
    __syncthreads();
#pragma unroll
    for (int kk = 0; kk < 8; kk++) {
      int kl = kp*8 + kk;
      float wv = Wl[kl*3 + ml];
      acc0 += wv * xl[kl*36 + bg*2];
      acc1 += wv * xl[kl*36 + bg*2 + 1];
    }
  }
  __syncthreads();
  for (int rd = 0; rd < 8; rd++) {
    if (kp == rd) {
      float* pr = part + ml*36 + bg*2;
      if (rd == 0) { pr[0] = acc0; pr[1] = acc1; }
      else         { pr[0] += acc0; pr[1] += acc1; }
    }
    __syncthreads();
  }
  if (tid < 64) {
    int ml2 = tid >> 5, b = tid & 31;
    int m = bid*2 + ml2;
    float s = part[ml2*36 + b] + P.bm[m];
    P.projT[m*32 + b] = (s > 0.f) ? s : 0.01f*s;
  }
}

// ---------------- logits chunk (64 v) reg-tiled GEMM + per-chunk partials (500 blocks)
__global__ __launch_bounds__(256) void k_logits(DecArgs P) {
  __shared__ float sm[9600];
  int bid = blockIdx.x, tid = threadIdx.x;
  const int v0 = bid * 64;
  float* Wl   = sm;            // [64k][68]
  float* pl   = sm + 4352;     // [64k][32]
  float* part = sm + 6400;     // [32b][68]
  const int kp = tid >> 5, vg = (tid >> 2) & 7, bg = tid & 3;
  const int sr = tid >> 2, skq = tid & 3;
  float acc[64];
#pragma unroll
  for (int i = 0; i < 64; i++) acc[i] = 0.f;

  const float* wrow = P.W_emb + (size_t)(v0 + sr)*H_ + skq*16;
  const float4* pbase = (const float4*)P.projT;
  float4 t0 = *((const float4*)(wrow + 0));
  float4 t1 = *((const float4*)(wrow + 4));
  float4 t2 = *((const float4*)(wrow + 8));
  float4 t3 = *((const float4*)(wrow + 12));
  float4 u0 = pbase[tid];
  float4 u1 = pbase[tid + 256];

  for (int w = 0; w < 8; w++) {
    __syncthreads();
    int kb = skq*16;
    Wl[(kb+ 0)*68+sr]=t0.x; Wl[(kb+ 1)*68+sr]=t0.y; Wl[(kb+ 2)*68+sr]=t0.z; Wl[(kb+ 3)*68+sr]=t0.w;
    Wl[(kb+ 4)*68+sr]=t1.x; Wl[(kb+ 5)*68+sr]=t1.y; Wl[(kb+ 6)*68+sr]=t1.z; Wl[(kb+ 7)*68+sr]=t1.w;
    Wl[(kb+ 8)*68+sr]=t2.x; Wl[(kb+ 9)*68+sr]=t2.y; Wl[(kb+10)*68+sr]=t2.z; Wl[(kb+11)*68+sr]=t2.w;
    Wl[(kb+12)*68+sr]=t3.x; Wl[(kb+13)*68+sr]=t3.y; Wl[(kb+14)*68+sr]=t3.z; Wl[(kb+15)*68+sr]=t3.w;
    ((float4*)pl)[tid]       = u0;
    ((float4*)pl)[tid + 256] = u1;
    __syncthreads();
    if (w < 7) {
      const float* wn = wrow + (w+1)*64;
      t0 = *((const float4*)(wn + 0));
      t1 = *((const float4*)(wn + 4));
      t2 = *((const float4*)(wn + 8));
      t3 = *((const float4*)(wn + 12));
      u0 = pbase[(w+1)*512 + tid];
      u1 = pbase[(w+1)*512 + tid + 256];
    }
#pragma unroll
    for (int kk = 0; kk < 8; kk++) {
      int kl = kp*8 + kk;
      float4 wv0 = *((const float4*)(Wl + kl*68 + vg*8));
      float4 wv1 = *((const float4*)(Wl + kl*68 + vg*8 + 4));
      float4 pv0 = *((const float4*)(pl + kl*32 + bg*8));
      float4 pv1 = *((const float4*)(pl + kl*32 + bg*8 + 4));
      float wa[8] = {wv0.x,wv0.y,wv0.z,wv0.w,wv1.x,wv1.y,wv1.z,wv1.w};
      float pa[8] = {pv0.x,pv0.y,pv0.z,pv0.w,pv1.x,pv1.y,pv1.z,pv1.w};
#pragma unroll
      for (int i = 0; i < 8; i++)
#pragma unroll
        for (int j = 0; j < 8; j++)
          acc[i*8+j] += wa[i]*pa[j];
    }
  }
  __syncthreads();
  if (kp == 0) {
#pragma unroll
    for (int j = 0; j < 8; j++) {
      int b = bg*8 + j;
      *((float4*)(part + b*68 + vg*8))     = make_float4(acc[0*8+j], acc[1*8+j], acc[2*8+j], acc[3*8+j]);
      *((float4*)(part + b*68 + vg*8 + 4)) = make_float4(acc[4*8+j], acc[5*8+j], acc[6*8+j], acc[7*8+j]);
    }
  }
  __syncthreads();
  for (int rd = 1; rd < 8; rd++) {
    if (kp == rd) {
#pragma unroll
      for (int j = 0; j < 8; j++) {
        int b = bg*8 + j;
        float4* q0 = (float4*)(part + b*68 + vg*8);
        float4* q1 = q0 + 1;
        float4 a0 = *q0, a1 = *q1;
        a0.x += acc[0*8+j]; a0.y += acc[1*8+j]; a0.z += acc[2*8+j]; a0.w += acc[3*8+j];
        a1.x += acc[4*8+j]; a1.y += acc[5*8+j]; a1.z += acc[6*8+j]; a1.w += acc[7*8+j];
        *q0 = a0; *q1 = a1;
      }
    }
    __syncthreads();
  }
  int b = tid >> 3, vq = tid & 7;
  float4 pA = *((const float4*)(part + b*68 + vq*8));
  float4 pB = *((const float4*)(part + b*68 + vq*8 + 4));
  int vb = v0 + vq*8;
  float x[8] = {pA.x,pA.y,pA.z,pA.w,pB.x,pB.y,pB.z,pB.w};
#pragma unroll
  for (int i = 0; i < 8; i++) x[i] += P.b_proj[vb + i];
  *((float4*)(P.logits + (size_t)b*V_ + vb))     = make_float4(x[0],x[1],x[2],x[3]);
  *((float4*)(P.logits + (size_t)b*V_ + vb + 4)) = make_float4(x[4],x[5],x[6],x[7]);
  float m = x[0], s = 1.f; int mi = vb;
#pragma unroll
  for (int i = 1; i < 8; i++) {
    if (x[i] > m) { s = s*expf(m - x[i]) + 1.f; m = x[i]; mi = vb + i; }
    else          { s += expf(x[i] - m); }
  }
  float* rm = sm; float* rs = sm + 256; int* ri = (int*)(sm + 512);
  __syncthreads();   // done with Wl region
  rm[vq*32 + b] = m; rs[vq*32 + b] = s; ri[vq*32 + b] = mi;
  __syncthreads();
  if (tid < 32) {
    int bb = tid;
    float M = rm[bb], S = rs[bb]; int I = ri[bb];
#pragma unroll
    for (int g = 1; g < 8; g++) {
      float m2 = rm[g*32+bb], s2 = rs[g*32+bb]; int i2 = ri[g*32+bb];
      if (m2 > M)       { S = S*expf(M - m2) + s2; M = m2; I = i2; }
      else if (m2 == M) { S += s2; I = min(I, i2); }
      else              { S += s2*expf(m2 - M); }
    }
    P.pm[bid*32 + bb] = M; P.ps[bid*32 + bb] = S; P.pidx[bid*32 + bb] = I;
  }
}

// ---------------- merge chunk partials -> lse[b], idx[b]  (32 blocks, one per b)
__global__ __launch_bounds__(256) void k_merge(DecArgs P) {
  __shared__ float sfm[256], sfs[256];
  __shared__ int   sii[256];
  int b = blockIdx.x, tid = threadIdx.x;
  float M = P.pm[tid*32 + b], S = P.ps[tid*32 + b]; int I = P.pidx[tid*32 + b];
  int c2 = tid + 256;
  if (c2 < NCHUNK) {
    float m2 = P.pm[c2*32+b], s2 = P.ps[c2*32+b]; int i2 = P.pidx[c2*32+b];
    if (m2 > M)       { S = S*expf(M - m2) + s2; M = m2; I = i2; }
    else if (m2 == M) { S += s2; I = min(I, i2); }
    else              { S += s2*expf(m2 - M); }
  }
  sfm[tid] = M; sfs[tid] = S; sii[tid] = I;
  __syncthreads();
  for (int st = 128; st > 0; st >>= 1) {
    if (tid < st) {
      float m1 = sfm[tid], s1 = sfs[tid]; int i1 = sii[tid];
      float m2 = sfm[tid+st], s2 = sfs[tid+st]; int i2 = sii[tid+st];
      float Mn, Sn; int In;
      if (m2 > m1)      { Mn = m2; Sn = s1*expf(m1-m2) + s2; In = i2; }
      else if (m2 < m1) { Mn = m1; Sn = s1 + s2*expf(m2-m1); In = i1; }
      else              { Mn = m1; Sn = s1 + s2; In = min(i1, i2); }
      sfm[tid] = Mn; sfs[tid] = Sn; sii[tid] = In;
    }
    __syncthreads();
  }
  if (tid == 0) { P.lse[b] = sfm[0] + logf(sfs[0]); P.idx[b] = sii[0]; }
}

// ---------------- final out write (step L-1), 256 blocks
__global__ __launch_bounds__(256) void k_finalout(DecArgs P) {
  int bid = blockIdx.x, tid = threadIdx.x;
  int b = bid & 31, vs = bid >> 5;
  float l = P.lse[b];
  const float4* lg = (const float4*)(P.logits + (size_t)b*V_ + vs*4000);
  float4* o4 = (float4*)(P.out + ((size_t)b*P.L + (P.L-1))*V_ + vs*4000);
  for (int i = tid; i < 1000; i += 256) {
    float4 x = lg[i];
    o4[i] = make_float4(x.x-l, x.y-l, x.z-l, x.w-l);
  }
}

extern "C" void kernel_launch(void* const* d_in, const int* in_sizes, int n_in,
                              void* d_out, int out_size, void* d_ws, size_t ws_size,
                              hipStream_t stream) {
  DecArgs P;
  P.key      = (const float*)d_in[0];
  P.value    = (const float*)d_in[1];
  P.src_lens = (const int*)d_in[4];
  P.W_emb    = (const float*)d_in[5];
  P.b_proj   = (const float*)d_in[6];
  P.Wq       = (const float*)d_in[7];
  P.bq       = (const float*)d_in[8];
  P.W_ih     = (const float*)d_in[9];
  P.W_hh     = (const float*)d_in[10];
  P.b_ih     = (const float*)d_in[11];
  P.b_hh     = (const float*)d_in[12];
  P.Wm       = (const float*)d_in[13];
  P.bm       = (const float*)d_in[14];
  P.h00      = (const float*)d_in[15];
  P.c00      = (const float*)d_in[16];
  P.out      = (float*)d_out;
  P.L        = in_sizes[2] / B_;

  float* ws = (float*)d_ws;
  P.hA     = ws; ws += B_*H_;
  P.hB     = ws; ws += B_*H_;
  P.c      = ws; ws += B_*H_;
  P.ctx    = ws; ws += B_*VD_;
  P.projT  = ws; ws += H_*B_;
  P.lse    = ws; ws += 32;
  P.pm     = ws; ws += NCHUNK*B_;
  P.ps     = ws; ws += NCHUNK*B_;
  P.logits = ws; ws += (size_t)B_*V_;
  P.pidx   = (int*)ws; ws += NCHUNK*B_;
  P.idx    = (int*)ws;

  k_init<<<64, 256, 0, stream>>>(P);
  k_att<<<256, 256, 0, stream>>>(P, P.hA);   // prologue attend with h0

  for (int s = 0; s < P.L; s++) {
    const float* hin  = (s & 1) ? P.hB : P.hA;
    float*       hout = (s & 1) ? P.hA : P.hB;
    k_gatesout<<<512, 256, 0, stream>>>(P, hin, hout, s);
    k_att<<<256, 256, 0, stream>>>(P, hout);
    k_proj<<<256, 256, 0, stream>>>(P);
    k_logits<<<NCHUNK, 256, 0, stream>>>(P);
    k_merge<<<32, 256, 0, stream>>>(P);
  }
  k_finalout<<<256, 256, 0, stream>>>(P);
}